// Round 1
// baseline (1225.551 us; speedup 1.0000x reference)
//
#include <hip/hip_runtime.h>
#include <math.h>

// Problem constants (D=1):
//   L=4096, c_a=128, c_pair=16, H=4, dh=32, k=128
// Workspace layout (floats): q | kk | v | g | gated, each 4096*128 -> 10 MiB total.

typedef float f4 __attribute__((ext_vector_type(4)));

__device__ __forceinline__ float dot4(f4 a, f4 b) {
  return a.x * b.x + a.y * b.y + a.z * b.z + a.w * b.w;
}

// ---------------------------------------------------------------------------
// Kernel 1: a = RMS(Q_L, ln1); q,kk,v,g = a @ {Wq,Wk,Wv,Wg}^T; q,kk post-RMS;
// g = sigmoid. 256 blocks x 256 threads, 16 rows/block.
// Thread (tx in [0,64), ty in [0,4)): cols {tx, tx+64}, rows {4ty..4ty+3},
// all 4 matrices fused in the inner loop (amortizes the aS broadcast reads:
// 12 b128 LDS reads per 128 FMA).
// ---------------------------------------------------------------------------
__global__ __launch_bounds__(256) void k_proj(
    const float* __restrict__ Q, const float* __restrict__ Wq,
    const float* __restrict__ Wk, const float* __restrict__ Wv,
    const float* __restrict__ Wg, const float* __restrict__ ln1,
    const float* __restrict__ lnq, const float* __restrict__ lnk,
    float* __restrict__ qo, float* __restrict__ ko,
    float* __restrict__ vo, float* __restrict__ go)
{
  __shared__ f4 aS4[16][32];        // 16 rows x 128 floats
  __shared__ f4 wT4[4][128][5];     // 4 mats x 128 rows x 16-float chunk (pitch 5 f4)
  __shared__ float scaleS[16];
  __shared__ float lnqS[128], lnkS[128];
  float* aS = (float*)aS4;

  const int tid = threadIdx.x;
  const int l0 = blockIdx.x * 16;

  if (tid < 128) { lnqS[tid] = lnq[tid]; lnkS[tid] = lnk[tid]; }

  // stage 16 Q rows
  const f4* Q4 = (const f4*)Q;
#pragma unroll
  for (int i = 0; i < 2; ++i) {
    int f = tid + 256 * i;               // 0..511
    int row = f >> 5, c4 = f & 31;
    aS4[row][c4] = Q4[(size_t)(l0 + row) * 32 + c4];
  }
  __syncthreads();

  // per-row sum of squares: 16 lanes per row
  {
    int r = tid >> 4, s = tid & 15;
    float ss = 0.f;
#pragma unroll
    for (int cc = 0; cc < 8; ++cc) {
      float x = aS[r * 128 + s + cc * 16];
      ss += x * x;
    }
#pragma unroll
    for (int off = 8; off; off >>= 1) ss += __shfl_xor(ss, off, 64);
    if (s == 0) scaleS[r] = rsqrtf(ss * (1.f / 128.f) + 1e-5f);
  }
  __syncthreads();
#pragma unroll
  for (int i = 0; i < 8; ++i) {
    int f = tid + 256 * i;
    int row = f >> 7;
    aS[f] = aS[f] * scaleS[row] * ln1[f & 127];
  }

  const float* Ws[4] = {Wq, Wk, Wv, Wg};
  float acc0[4][4], acc1[4][4];
#pragma unroll
  for (int m = 0; m < 4; ++m)
#pragma unroll
    for (int rr = 0; rr < 4; ++rr) { acc0[m][rr] = 0.f; acc1[m][rr] = 0.f; }

  const int tx = tid & 63, ty = tid >> 6;

  for (int c0 = 0; c0 < 128; c0 += 16) {
    __syncthreads();  // also covers the aS normalize on first iteration
#pragma unroll
    for (int i = 0; i < 8; ++i) {
      int f = tid + 256 * i;             // 0..2047 = 4 mats x 128 rows x 4 f4
      int m = f >> 9;
      int rem = f & 511;
      int trow = rem >> 2, c4 = rem & 3;
      wT4[m][trow][c4] = ((const f4*)Ws[m])[trow * 32 + (c0 >> 2) + c4];
    }
    __syncthreads();
#pragma unroll
    for (int cc4 = 0; cc4 < 4; ++cc4) {
      f4 a[4];
#pragma unroll
      for (int rr = 0; rr < 4; ++rr) a[rr] = aS4[ty * 4 + rr][(c0 >> 2) + cc4];
#pragma unroll
      for (int m = 0; m < 4; ++m) {
        f4 w0 = wT4[m][tx][cc4];
        f4 w1 = wT4[m][tx + 64][cc4];
#pragma unroll
        for (int rr = 0; rr < 4; ++rr) {
          acc0[m][rr] += dot4(a[rr], w0);
          acc1[m][rr] += dot4(a[rr], w1);
        }
      }
    }
  }

  // epilogue: rows 4ty..4ty+3 live entirely in wave ty (tid>>6 == wave id)
#pragma unroll
  for (int rr = 0; rr < 4; ++rr) {
    int r = ty * 4 + rr;
    size_t base = (size_t)(l0 + r) * 128;

    float q0 = acc0[0][rr], q1 = acc1[0][rr];
    float ss = q0 * q0 + q1 * q1;
#pragma unroll
    for (int off = 32; off; off >>= 1) ss += __shfl_xor(ss, off, 64);
    float sc = rsqrtf(ss * (1.f / 128.f) + 1e-5f);
    qo[base + tx]      = q0 * sc * lnqS[tx];
    qo[base + tx + 64] = q1 * sc * lnqS[tx + 64];

    float k0 = acc0[1][rr], k1 = acc1[1][rr];
    ss = k0 * k0 + k1 * k1;
#pragma unroll
    for (int off = 32; off; off >>= 1) ss += __shfl_xor(ss, off, 64);
    sc = rsqrtf(ss * (1.f / 128.f) + 1e-5f);
    ko[base + tx]      = k0 * sc * lnkS[tx];
    ko[base + tx + 64] = k1 * sc * lnkS[tx + 64];

    vo[base + tx]      = acc0[2][rr];
    vo[base + tx + 64] = acc1[2][rr];

    go[base + tx]      = 1.f / (1.f + expf(-acc0[3][rr]));
    go[base + tx + 64] = 1.f / (1.f + expf(-acc1[3][rr]));
  }
}

// ---------------------------------------------------------------------------
// Kernel 2: per-query attention. One block per l (4096 blocks, 256 threads).
//  - gather 64 K rows at a time into LDS (coalesced f4), swizzled slot layout
//  - thread (jr,h) computes score + pair-bias (P gathered nontemporally)
//  - softmax: one wave per head
//  - PV: thread = output channel c, coalesced V gathers, attn broadcast
// ---------------------------------------------------------------------------
__global__ __launch_bounds__(256) void k_attn(
    const float* __restrict__ P, const int* __restrict__ idx,
    const float* __restrict__ Wb,
    const float* __restrict__ qw, const float* __restrict__ kw,
    const float* __restrict__ vw, const float* __restrict__ gw,
    float* __restrict__ gated)
{
  __shared__ f4 Kt4[64][33];       // 64 gathered K rows (pitch 33 f4)
  __shared__ float sS[4][128];     // scores -> attn
  __shared__ float oPart[2][128];
  __shared__ float qS[128], gS[128];
  __shared__ int idxS[128];
  __shared__ f4 WbS4[4][4];        // Wb[4][16]

  const int tid = threadIdx.x;
  const int l = blockIdx.x;

  if (tid < 128) {
    qS[tid] = qw[(size_t)l * 128 + tid];
    gS[tid] = gw[(size_t)l * 128 + tid];
    idxS[tid] = idx[(size_t)l * 128 + tid];
  } else if (tid < 192) {
    ((float*)WbS4)[tid - 128] = Wb[tid - 128];
  }
  __syncthreads();

  const f4* K4g = (const f4*)kw;
  const f4* qS4 = (const f4*)qS;
  const float inv_s = 0.17677669529663687f;  // 1/sqrt(32)

  const int jr = tid >> 2;  // 0..63
  const int h = tid & 3;    // head

  for (int hj = 0; hj < 2; ++hj) {
    // stage 64 K rows; slot swizzle so (h,cc) reads avoid the 8-f4-stride
    // bank degeneracy: global chunk c4 -> slot (c4&7)*4 + (c4>>3)
#pragma unroll
    for (int i = 0; i < 8; ++i) {
      int f = tid + 256 * i;   // 0..2047
      int r = f >> 5, c4 = f & 31;
      int row = idxS[hj * 64 + r];
      int slot = (c4 & 7) * 4 + (c4 >> 3);
      Kt4[r][slot] = K4g[(size_t)row * 32 + c4];
    }
    __syncthreads();
    {
      float sc = 0.f;
#pragma unroll
      for (int cc = 0; cc < 8; ++cc)
        sc += dot4(Kt4[jr][cc * 4 + h], qS4[h * 8 + cc]);
      int j = hj * 64 + jr;
      int row = idxS[j];
      const f4* Pr = (const f4*)(P + ((size_t)l * 4096 + (size_t)row) * 16);
      float b = 0.f;
#pragma unroll
      for (int i = 0; i < 4; ++i) {
        f4 pv = __builtin_nontemporal_load(Pr + i);  // don't pollute L2
        b += dot4(pv, WbS4[h][i]);
      }
      sS[h][j] = sc * inv_s + b;
    }
    __syncthreads();
  }

  // softmax over j=128, one wave per head
  {
    int hw = tid >> 6, lane = tid & 63;
    float s0 = sS[hw][lane], s1 = sS[hw][lane + 64];
    float m = fmaxf(s0, s1);
#pragma unroll
    for (int off = 32; off; off >>= 1) m = fmaxf(m, __shfl_xor(m, off, 64));
    float e0 = expf(s0 - m), e1 = expf(s1 - m);
    float t = e0 + e1;
#pragma unroll
    for (int off = 32; off; off >>= 1) t += __shfl_xor(t, off, 64);
    float riv = 1.f / t;
    sS[hw][lane] = e0 * riv;
    sS[hw][lane + 64] = e1 * riv;
  }
  __syncthreads();

  // PV: thread = (channel c, half jh); V gathers coalesced per j
  {
    const int c = tid & 127, jh = tid >> 7;
    const int hh = c >> 5;
    float acc = 0.f;
    for (int jj = 0; jj < 64; ++jj) {
      int j = jh * 64 + jj;
      int row = idxS[j];
      acc += sS[hh][j] * vw[(size_t)row * 128 + c];
    }
    oPart[jh][c] = acc;
  }
  __syncthreads();
  if (tid < 128)
    gated[(size_t)l * 128 + tid] = (oPart[0][tid] + oPart[1][tid]) * gS[tid];
}

// ---------------------------------------------------------------------------
// Kernel 3: out = gated @ Wo^T. Same GEMM skeleton as k_proj, single matrix.
// ---------------------------------------------------------------------------
__global__ __launch_bounds__(256) void k_out(
    const float* __restrict__ X, const float* __restrict__ Wo,
    float* __restrict__ out)
{
  __shared__ f4 aS4[16][32];
  __shared__ f4 wT4[128][9];   // 32-float chunk, pitch 9 f4
  const int tid = threadIdx.x;
  const int l0 = blockIdx.x * 16;
  const f4* X4 = (const f4*)X;
#pragma unroll
  for (int i = 0; i < 2; ++i) {
    int f = tid + 256 * i;
    aS4[f >> 5][f & 31] = X4[(size_t)(l0 + (f >> 5)) * 32 + (f & 31)];
  }
  float acc0[4], acc1[4];
#pragma unroll
  for (int rr = 0; rr < 4; ++rr) { acc0[rr] = 0.f; acc1[rr] = 0.f; }
  const int tx = tid & 63, ty = tid >> 6;
  const f4* W4 = (const f4*)Wo;
  for (int c0 = 0; c0 < 128; c0 += 32) {
    __syncthreads();
#pragma unroll
    for (int i = 0; i < 4; ++i) {
      int f = tid + 256 * i;  // 0..1023
      int trow = f >> 3, c4 = f & 7;
      wT4[trow][c4] = W4[trow * 32 + (c0 >> 2) + c4];
    }
    __syncthreads();
#pragma unroll
    for (int cc4 = 0; cc4 < 8; ++cc4) {
      f4 w0 = wT4[tx][cc4], w1 = wT4[tx + 64][cc4];
#pragma unroll
      for (int rr = 0; rr < 4; ++rr) {
        f4 a4 = aS4[ty * 4 + rr][(c0 >> 2) + cc4];
        acc0[rr] += dot4(a4, w0);
        acc1[rr] += dot4(a4, w1);
      }
    }
  }
#pragma unroll
  for (int rr = 0; rr < 4; ++rr) {
    size_t base = (size_t)(l0 + ty * 4 + rr) * 128;
    out[base + tx]      = acc0[rr];
    out[base + tx + 64] = acc1[rr];
  }
}

extern "C" void kernel_launch(void* const* d_in, const int* in_sizes, int n_in,
                              void* d_out, int out_size, void* d_ws, size_t ws_size,
                              hipStream_t stream) {
  const float* Q   = (const float*)d_in[0];
  const float* P   = (const float*)d_in[1];
  const int*   idx = (const int*)d_in[2];
  const float* Wq  = (const float*)d_in[3];
  const float* Wk  = (const float*)d_in[4];
  const float* Wv  = (const float*)d_in[5];
  const float* Wg  = (const float*)d_in[6];
  const float* Wb  = (const float*)d_in[7];
  const float* Wo  = (const float*)d_in[8];
  const float* ln1 = (const float*)d_in[9];
  const float* lnq = (const float*)d_in[10];
  const float* lnk = (const float*)d_in[11];
  float* out = (float*)d_out;
  float* ws = (float*)d_ws;

  const size_t SZ = (size_t)4096 * 128;
  float* qw = ws;
  float* kw = ws + SZ;
  float* vw = ws + 2 * SZ;
  float* gw = ws + 3 * SZ;
  float* gt = ws + 4 * SZ;   // needs 10 MiB of d_ws

  hipLaunchKernelGGL(k_proj, dim3(256), dim3(256), 0, stream,
                     Q, Wq, Wk, Wv, Wg, ln1, lnq, lnk, qw, kw, vw, gw);
  hipLaunchKernelGGL(k_attn, dim3(4096), dim3(256), 0, stream,
                     P, idx, Wb, qw, kw, vw, gw, gt);
  hipLaunchKernelGGL(k_out, dim3(256), dim3(256), 0, stream, gt, Wo, out);
}